// Round 2
// baseline (511.882 us; speedup 1.0000x reference)
//
#include <hip/hip_runtime.h>
#include <hip/hip_bf16.h>

// ---------------------------------------------------------------------------
// GINE GNN. Features: f16 plane (self/MLP) + fp8-e4m3 shadow plane gathered
// by k_agg (halves per-XCD L2-fill). CSR build: global counting sort
// (k_cnt degree atomics -> 3-kernel scan -> k_place direct placement with
// RTN cursor atomics), which replaces the old bucket-bin/bucket-sort pair
// (k_bin2+k_fill2, ~90us of LDS-atomic-bound latency) with ~30us of
// streaming kernels. Layer-0 edge messages aggregate via global f32 atomics
// in k_place (more accurate than the old f16 path). Weights prefragmented
// f16 MFMA.
// ---------------------------------------------------------------------------

#define HID 128
#define NCLS 3

typedef _Float16 f16;
typedef f16 f16x2 __attribute__((ext_vector_type(2)));
typedef f16 f16x8 __attribute__((ext_vector_type(8)));
typedef float f32x2 __attribute__((ext_vector_type(2)));
typedef float f32x4 __attribute__((ext_vector_type(4)));
typedef unsigned short ushort;

__device__ __forceinline__ float bcf(int v) {
    return __builtin_bit_cast(float, v);
}

// ---- CSR build pass 1: per-node degree ------------------------------------

__global__ __launch_bounds__(256) void k_cnt(const int* __restrict__ dst,
                                             int* __restrict__ deg, int E) {
    int base = blockIdx.x * 2048 + threadIdx.x;
    #pragma unroll
    for (int j = 0; j < 8; ++j) {
        int e = base + j * 256;
        if (e < E) atomicAdd(&deg[dst[e]], 1);
    }
}

// ---- scan: block-local inclusive (98 x 1024), block sums, carry, finalize -

__global__ __launch_bounds__(1024) void k_scan1(const int* __restrict__ deg,
                                                int* __restrict__ incl,
                                                int* __restrict__ bsum, int N) {
    __shared__ int sd[1024];
    int t = threadIdx.x, i = blockIdx.x * 1024 + t;
    int v = (i < N) ? deg[i] : 0;
    sd[t] = v;
    __syncthreads();
    #pragma unroll
    for (int o = 1; o < 1024; o <<= 1) {
        int add = (t >= o) ? sd[t - o] : 0;
        __syncthreads();
        sd[t] += add;
        __syncthreads();
    }
    if (i < N) incl[i] = sd[t];
    if (t == 1023) bsum[blockIdx.x] = sd[t];
}

__global__ __launch_bounds__(128) void k_scan2(const int* __restrict__ bsum,
                                               int* __restrict__ carry, int NSB) {
    __shared__ int sd[128];
    int t = threadIdx.x;
    int v = (t < NSB) ? bsum[t] : 0;
    sd[t] = v;
    __syncthreads();
    #pragma unroll
    for (int o = 1; o < 128; o <<= 1) {
        int add = (t >= o) ? sd[t - o] : 0;
        __syncthreads();
        sd[t] += add;
        __syncthreads();
    }
    if (t < NSB) carry[t] = sd[t] - v;        // exclusive block offset
}

__global__ __launch_bounds__(1024) void k_scan3(const int* __restrict__ deg,
                                                const int* __restrict__ incl,
                                                const int* __restrict__ carry,
                                                int2* __restrict__ meta,
                                                int* __restrict__ cur, int N) {
    int i = blockIdx.x * 1024 + threadIdx.x;
    if (i < N) {
        int d = deg[i];
        int o = carry[blockIdx.x] + incl[i] - d;
        meta[i] = make_int2(o, d);
        cur[i] = o;
    }
}

// ---- graph-segment prep (was in k_fill2) ----------------------------------

__global__ __launch_bounds__(256) void k_gseg(const int* __restrict__ batch,
                                              int* __restrict__ gcount,
                                              int* __restrict__ gstart, int N) {
    int i = blockIdx.x * 256 + threadIdx.x;
    if (i < N) {
        int gb = batch[i];
        atomicAdd(&gcount[gb], 1);
        if (i == 0 || batch[i - 1] != gb) gstart[gb] = i;
    }
}

// ---- CSR build pass 2: direct placement + layer-0 message aggregation -----
// pairs.x = src*128 byte offset (fp8 plane); pairs.y = f32 attr bits.

__global__ __launch_bounds__(256) void k_place(const int* __restrict__ src,
                                               const int* __restrict__ dst,
                                               const float* __restrict__ eattr,
                                               const float* __restrict__ x,
                                               int* __restrict__ cur,
                                               int2* __restrict__ pairs,
                                               float* __restrict__ agg0, int E) {
    int base = blockIdx.x * 2048 + threadIdx.x;
    int s[8], d[8];
    float at[8], xs[8];
    #pragma unroll
    for (int j = 0; j < 8; ++j) {
        int e = base + j * 256;
        s[j] = 0; d[j] = 0; at[j] = 0.f;
        if (e < E) {
            s[j] = src[e];
            d[j] = dst[e];
            at[j] = eattr[e];
        }
    }
    #pragma unroll
    for (int j = 0; j < 8; ++j) xs[j] = x[s[j]];
    int r[8];
    #pragma unroll
    for (int j = 0; j < 8; ++j) {
        int e = base + j * 256;
        if (e < E) r[j] = atomicAdd(&cur[d[j]], 1);
    }
    #pragma unroll
    for (int j = 0; j < 8; ++j) {
        int e = base + j * 256;
        if (e < E) {
            pairs[r[j]] = make_int2(s[j] << 7,
                                    __builtin_bit_cast(int, at[j]));
            float msg = fmaxf(xs[j] + at[j], 0.f);
            atomicAdd(&agg0[d[j]], msg);
        }
    }
}

// ---- prep: W prefragmentation (f16 per-lane MFMA layout), 14 blocks -------

__global__ __launch_bounds__(1024) void k_prep(const float* __restrict__ W2_0,
                                               const float* __restrict__ W1_s,
                                               const float* __restrict__ W2_s,
                                               f16* __restrict__ Wf) {
    int t = threadIdx.x;
    int id = blockIdx.x * 1024 + t;         // [0, 14336)
    int lane = id & 63;
    int w    = (id >> 6) & 3;
    int nf   = (id >> 8) & 1;
    int kk   = (id >> 9) & 3;
    int g    = id >> 11;
    const float* W = (g == 0) ? W2_0
                   : ((g & 1) ? W1_s + (size_t)((g - 1) >> 1) * HID * HID
                              : W2_s + (size_t)((g - 2) >> 1) * HID * HID);
    int col = w * 32 + nf * 16 + (lane & 15);
    int k0  = kk * 32 + (lane >> 4) * 8;
    f16x8 hi;
    #pragma unroll
    for (int j = 0; j < 8; ++j)
        hi[j] = (f16)W[(k0 + j) * HID + col];
    size_t o = ((((size_t)g * 4 + kk) * 2 + nf) * 4 + w) * 512 +
               (size_t)lane * 8;
    *(f16x8*)&Wf[o] = hi;
}

// ---- 128-wide aggregation: wave/node, fp8 gather, f32 packed math ---------

__device__ __forceinline__ void agg_add8(f32x2 acc2[4], uint2 g, float e) {
    f32x2 e2 = {e, e}, z2 = {0.f, 0.f};
    unsigned gw[2] = {g.x, g.y};
    #pragma unroll
    for (int ww = 0; ww < 2; ++ww) {
        f32x2 lo = __builtin_amdgcn_cvt_pk_f32_fp8((int)gw[ww], false);
        f32x2 hi = __builtin_amdgcn_cvt_pk_f32_fp8((int)gw[ww], true);
        lo = __builtin_elementwise_max(lo + e2, z2);
        hi = __builtin_elementwise_max(hi + e2, z2);
        acc2[2 * ww]     += lo;
        acc2[2 * ww + 1] += hi;
    }
}

__device__ __forceinline__ uint2 agg_ld8(const char* __restrict__ hb,
                                         int voff) {
    return *(const uint2*)(hb + (unsigned)voff);
}

__global__ __launch_bounds__(256) void k_agg(const unsigned char* __restrict__ h8,
                                             const f16* __restrict__ hf,
                                             const int2* __restrict__ pairs,
                                             const int2* __restrict__ meta,
                                             f16* __restrict__ oh, int n) {
    int gw = (blockIdx.x * 256 + threadIdx.x) >> 6;
    if (gw >= n) return;               // wave-uniform exit
    int lane = threadIdx.x & 63;
    int q = lane >> 4, c = lane & 15;
    int c8 = c * 8;
    const char* hb = (const char*)h8;
    int2 m = meta[gw];
    int off = m.x, d = m.y;
    f32x2 acc2[4] = {{0.f,0.f},{0.f,0.f},{0.f,0.f},{0.f,0.f}};

    int2 mypr = make_int2(0, 0);
    if (lane < d) mypr = pairs[off + lane];
    int lim = d < 64 ? d : 64;

    int pb = 0;
    for (; pb + 16 <= lim; pb += 16) {          // wave-uniform bound
        int p0 = pb + q;
        int s0 = __shfl(mypr.x, p0);
        int s1 = __shfl(mypr.x, p0 + 4);
        int s2 = __shfl(mypr.x, p0 + 8);
        int s3 = __shfl(mypr.x, p0 + 12);
        float e0 = bcf(__shfl(mypr.y, p0));
        float e1 = bcf(__shfl(mypr.y, p0 + 4));
        float e2 = bcf(__shfl(mypr.y, p0 + 8));
        float e3 = bcf(__shfl(mypr.y, p0 + 12));
        uint2 g0 = agg_ld8(hb, s0 + c8);
        uint2 g1 = agg_ld8(hb, s1 + c8);
        uint2 g2 = agg_ld8(hb, s2 + c8);
        uint2 g3 = agg_ld8(hb, s3 + c8);
        agg_add8(acc2, g0, e0);
        agg_add8(acc2, g1, e1);
        agg_add8(acc2, g2, e2);
        agg_add8(acc2, g3, e3);
    }
    if (pb < lim) {
        // single predicated step: pb <= 48 so all shuffle sources <= 63
        int pe = pb + q;
        int s0 = __shfl(mypr.x, pe);
        int s1 = __shfl(mypr.x, pe + 4);
        int s2 = __shfl(mypr.x, pe + 8);
        int s3 = __shfl(mypr.x, pe + 12);
        float e0 = bcf(__shfl(mypr.y, pe));
        float e1 = bcf(__shfl(mypr.y, pe + 4));
        float e2 = bcf(__shfl(mypr.y, pe + 8));
        float e3 = bcf(__shfl(mypr.y, pe + 12));
        uint2 g0 = agg_ld8(hb, s0 + c8);
        uint2 g1 = agg_ld8(hb, s1 + c8);
        uint2 g2 = agg_ld8(hb, s2 + c8);
        uint2 g3 = agg_ld8(hb, s3 + c8);
        if (pe < lim)      agg_add8(acc2, g0, e0);
        if (pe + 4 < lim)  agg_add8(acc2, g1, e1);
        if (pe + 8 < lim)  agg_add8(acc2, g2, e2);
        if (pe + 12 < lim) agg_add8(acc2, g3, e3);
    }
    for (int p = 64 + q; p < d; p += 4) {        // deg>64 tail, no shuffles
        int2 pr = pairs[off + p];
        agg_add8(acc2, agg_ld8(hb, pr.x + c8), bcf(pr.y));
    }

    #pragma unroll
    for (int ww = 0; ww < 4; ++ww) {
        acc2[ww].x += __shfl_xor(acc2[ww].x, 16);
        acc2[ww].x += __shfl_xor(acc2[ww].x, 32);
        acc2[ww].y += __shfl_xor(acc2[ww].y, 16);
        acc2[ww].y += __shfl_xor(acc2[ww].y, 32);
    }
    if (q == 0) {
        uint4 sg = *(const uint4*)&hf[(size_t)gw * HID + c * 8];
        unsigned sw[4] = {sg.x, sg.y, sg.z, sg.w};
        unsigned ow[4];
        #pragma unroll
        for (int ww = 0; ww < 4; ++ww) {
            f16x2 s = __builtin_bit_cast(f16x2, sw[ww]);
            f16x2 o;
            o[0] = (f16)((float)s[0] + acc2[ww].x);
            o[1] = (f16)((float)s[1] + acc2[ww].y);
            ow[ww] = __builtin_bit_cast(unsigned, o);
        }
        uint4 o4;
        o4.x = ow[0]; o4.y = ow[1]; o4.z = ow[2]; o4.w = ow[3];
        *(uint4*)&oh[(size_t)gw * HID + c * 8] = o4;
    }
}

// ---- MLP helpers (single-product f16 weights) -----------------------------

__device__ __forceinline__ void load_wfrags1(const f16* __restrict__ Wfg,
                                             int w, int lane,
                                             f16x8 whf[4][2]) {
    #pragma unroll
    for (int kk = 0; kk < 4; ++kk)
        #pragma unroll
        for (int nf = 0; nf < 2; ++nf) {
            size_t o = (((size_t)kk * 2 + nf) * 4 + w) * 512 +
                       (size_t)lane * 8;
            whf[kk][nf] = *(const f16x8*)&Wfg[o];
        }
}

__device__ __forceinline__ void do_gemm1(const f16* Ah,
                                         const f16x8 whf[4][2],
                                         int lane, f32x4 acc[4][2]) {
    int arow = lane & 15, akgrp = lane >> 4;
    #pragma unroll
    for (int kk = 0; kk < 4; ++kk) {
        int chunk = kk * 4 + akgrp;
        f16x8 ah[4];
        #pragma unroll
        for (int mf = 0; mf < 4; ++mf) {
            int r = mf * 16 + arow;
            int swz = chunk ^ (r & 15);
            ah[mf] = *(const f16x8*)&Ah[r * HID + swz * 8];
        }
        #pragma unroll
        for (int mf = 0; mf < 4; ++mf)
            #pragma unroll
            for (int nf = 0; nf < 2; ++nf)
                acc[mf][nf] = __builtin_amdgcn_mfma_f32_16x16x32_f16(
                    ah[mf], whf[kk][nf], acc[mf][nf], 0, 0, 0);
    }
}

// ---- MLP: O = relu(relu(A@W1+b1)@W2+b2), A f16 plane; fp8 shadow write ----

__global__ __launch_bounds__(256, 3) void k_mlp(
    const f16* __restrict__ A_g,
    const f16* __restrict__ Wf1, const float* __restrict__ b1,
    const f16* __restrict__ Wf2, const float* __restrict__ b2,
    f16* __restrict__ O, unsigned char* __restrict__ O8, int w8, int n) {

    __shared__ __align__(16) f16 bufA[64 * HID];   // A, then T
    int t = threadIdx.x, w = t >> 6, lane = t & 63;
    int wcol = w * 32, fcol = lane & 15, kgrp = lane >> 4;
    int row0 = blockIdx.x * 64;

    #pragma unroll
    for (int rep = 0; rep < 4; ++rep) {
        int task = rep * 256 + t;
        int r = task >> 4, ch = task & 15;
        int gr = min(row0 + r, n - 1);
        int swz = ch ^ (r & 15);
        *(f16x8*)&bufA[r * HID + swz * 8] =
            *(const f16x8*)&A_g[(size_t)gr * HID + ch * 8];
    }

    f32x4 acc[4][2];
    {
        f16x8 whf[4][2];
        load_wfrags1(Wf1, w, lane, whf);
        float bv0 = b1[wcol + fcol], bv1 = b1[wcol + 16 + fcol];
        __syncthreads();
        #pragma unroll
        for (int mf = 0; mf < 4; ++mf)
            #pragma unroll
            for (int nf = 0; nf < 2; ++nf)
                acc[mf][nf] = (f32x4)(0.f);
        do_gemm1(bufA, whf, lane, acc);
        __syncthreads();   // all A reads done before T overwrites
        #pragma unroll
        for (int mf = 0; mf < 4; ++mf)
            #pragma unroll
            for (int nf = 0; nf < 2; ++nf) {
                int cc = wcol + nf * 16 + fcol;
                float bb = nf ? bv1 : bv0;
                #pragma unroll
                for (int j = 0; j < 4; ++j) {
                    int r = mf * 16 + kgrp * 4 + j;
                    float v = fmaxf(acc[mf][nf][j] + bb, 0.f);
                    int addr = r * HID + (((cc >> 3) ^ (r & 15)) << 3) + (cc & 7);
                    bufA[addr] = (f16)v;
                }
            }
    }
    {
        f16x8 whf[4][2];
        load_wfrags1(Wf2, w, lane, whf);
        float bv0 = b2[wcol + fcol], bv1 = b2[wcol + 16 + fcol];
        __syncthreads();
        #pragma unroll
        for (int mf = 0; mf < 4; ++mf)
            #pragma unroll
            for (int nf = 0; nf < 2; ++nf)
                acc[mf][nf] = (f32x4)(0.f);
        do_gemm1(bufA, whf, lane, acc);

        #pragma unroll
        for (int mf = 0; mf < 4; ++mf)
            #pragma unroll
            for (int nf = 0; nf < 2; ++nf) {
                int cc = wcol + nf * 16 + fcol;
                float bb = nf ? bv1 : bv0;
                #pragma unroll
                for (int j = 0; j < 4; ++j) {
                    int r = row0 + mf * 16 + kgrp * 4 + j;
                    if (r < n) {
                        float v = fmaxf(acc[mf][nf][j] + bb, 0.f);
                        O[(size_t)r * HID + cc] = (f16)v;
                        if (w8) {
                            int pk = __builtin_amdgcn_cvt_pk_fp8_f32(
                                v, v, 0, false);
                            O8[(size_t)r * HID + cc] =
                                (unsigned char)(pk & 0xFF);
                        }
                    }
                }
            }
    }
}

// ---- layer-0 MLP (rank-1 expansion fused; input = x + agg0) ---------------

__global__ __launch_bounds__(256, 3) void k_mlp0(
    const float* __restrict__ x, const float* __restrict__ agg0,
    const float* __restrict__ r1w, const float* __restrict__ r1b,
    const f16* __restrict__ Wf2, const float* __restrict__ b2,
    f16* __restrict__ O, unsigned char* __restrict__ O8, int n) {

    __shared__ __align__(16) f16 bufA[64 * HID];
    int t = threadIdx.x, w = t >> 6, lane = t & 63;
    int wcol = w * 32, fcol = lane & 15, kgrp = lane >> 4;
    int row0 = blockIdx.x * 64;

    #pragma unroll
    for (int rep = 0; rep < 4; ++rep) {
        int task = rep * 256 + t;
        int r = task >> 4, ch = task & 15;
        int gr = min(row0 + r, n - 1);
        int swz = ch ^ (r & 15);
        float xv = x[gr] + agg0[gr];
        f16x8 hi;
        #pragma unroll
        for (int j = 0; j < 8; ++j)
            hi[j] = (f16)fmaxf(xv * r1w[ch * 8 + j] + r1b[ch * 8 + j], 0.f);
        *(f16x8*)&bufA[r * HID + swz * 8] = hi;
    }

    f16x8 whf[4][2];
    load_wfrags1(Wf2, w, lane, whf);
    float bv0 = b2[wcol + fcol], bv1 = b2[wcol + 16 + fcol];
    __syncthreads();
    f32x4 acc[4][2];
    #pragma unroll
    for (int mf = 0; mf < 4; ++mf)
        #pragma unroll
        for (int nf = 0; nf < 2; ++nf)
            acc[mf][nf] = (f32x4)(0.f);
    do_gemm1(bufA, whf, lane, acc);

    #pragma unroll
    for (int mf = 0; mf < 4; ++mf)
        #pragma unroll
        for (int nf = 0; nf < 2; ++nf) {
            int cc = wcol + nf * 16 + fcol;
            float bb = nf ? bv1 : bv0;
            #pragma unroll
            for (int j = 0; j < 4; ++j) {
                int r = row0 + mf * 16 + kgrp * 4 + j;
                if (r < n) {
                    float v = fmaxf(acc[mf][nf][j] + bb, 0.f);
                    O[(size_t)r * HID + cc] = (f16)v;
                    int pk = __builtin_amdgcn_cvt_pk_fp8_f32(v, v, 0, false);
                    O8[(size_t)r * HID + cc] = (unsigned char)(pk & 0xFF);
                }
            }
        }
}

// ---- mean pool + head: 256 threads, 4 rows in flight, f16x2 loads ---------

__global__ __launch_bounds__(256) void k_head(const f16* __restrict__ h,
                                              const int* __restrict__ gstart,
                                              const int* __restrict__ gcount,
                                              const float* __restrict__ Wc,
                                              const float* __restrict__ bc,
                                              float* __restrict__ out, int G) {
    __shared__ float2 red[4][64];
    __shared__ float pl[HID];
    int g = blockIdx.x, t = threadIdx.x;
    int rr = t >> 6, cc = t & 63;
    int st = gstart[g], c = gcount[g];
    float2 acc = make_float2(0.f, 0.f);
    for (int i = rr; i < c; i += 4) {
        unsigned u = *(const unsigned*)&h[(size_t)(st + i) * HID + cc * 2];
        f16x2 v = __builtin_bit_cast(f16x2, u);
        acc.x += (float)v[0];
        acc.y += (float)v[1];
    }
    red[rr][cc] = acc;
    __syncthreads();
    if (rr == 0) {
        #pragma unroll
        for (int k = 1; k < 4; ++k) {
            acc.x += red[k][cc].x;
            acc.y += red[k][cc].y;
        }
        float inv = 1.f / fmaxf((float)c, 1.f);
        pl[cc * 2]     = acc.x * inv;
        pl[cc * 2 + 1] = acc.y * inv;
    }
    __syncthreads();
    if (t < NCLS) {
        float o = bc[t];
        for (int k = 0; k < HID; ++k) o += pl[k] * Wc[k * NCLS + t];
        out[g * NCLS + t] = o;
    }
}

// ---------------------------------------------------------------------------

static inline size_t alignup(size_t x, size_t a) { return (x + a - 1) & ~(a - 1); }

extern "C" void kernel_launch(void* const* d_in, const int* in_sizes, int n_in,
                              void* d_out, int out_size, void* d_ws, size_t ws_size,
                              hipStream_t stream) {
    const float* x      = (const float*)d_in[0];
    const int*   ei     = (const int*)d_in[1];
    const float* eattr  = (const float*)d_in[2];
    const int*   batch  = (const int*)d_in[3];
    const float* W1_0   = (const float*)d_in[4];
    const float* b1_0   = (const float*)d_in[5];
    const float* W2_0   = (const float*)d_in[6];
    const float* b2_0   = (const float*)d_in[7];
    const float* W1_s   = (const float*)d_in[8];
    const float* b1_s   = (const float*)d_in[9];
    const float* W2_s   = (const float*)d_in[10];
    const float* b2_s   = (const float*)d_in[11];
    const float* Wc     = (const float*)d_in[12];
    const float* bc     = (const float*)d_in[13];

    const int N = in_sizes[0];          // 100000
    const int E = in_sizes[2];          // 1600000
    const int G = out_size / NCLS;      // 1000
    const int* srcI = ei;
    const int* dstI = ei + E;

    const int NSB = (N + 1023) / 1024;              // 98 scan blocks (<=128)
    const int EBLK = (E + 2047) / 2048;             // 782 edge-pass blocks

    char* p = (char*)d_ws;
    size_t off = 0;
    size_t gcount_off = off;         off = alignup(off + (size_t)G * 4, 256);
    size_t gstart_off = off;         off = alignup(off + (size_t)G * 4, 256);
    size_t deg_off = off;            off = alignup(off + (size_t)N * 4, 256);
    size_t agg0_off = off;           off = alignup(off + (size_t)N * 4, 256);
    size_t zero_bytes = off;
    size_t incl_off = off;           off = alignup(off + (size_t)N * 4, 256);
    size_t cur_off = off;            off = alignup(off + (size_t)N * 4, 256);
    size_t bsum_off = off;           off = alignup(off + 128 * 4, 256);
    size_t carry_off = off;          off = alignup(off + 128 * 4, 256);
    size_t meta_off = off;           off = alignup(off + (size_t)N * 8, 256);
    size_t wf_off = off;             off = alignup(off + 7 * 16384 * 2, 256);
    size_t pairs_off = off;          off = alignup(off + (size_t)E * 8, 256);
    size_t p0_off = off;             off = alignup(off + (size_t)N * HID * 2, 256);
    size_t p8_off = off;             off = alignup(off + (size_t)N * HID, 256);
    size_t p1_off = off;             off = alignup(off + (size_t)N * HID * 2, 256);

    int*    gcount  = (int*)(p + gcount_off);
    int*    gstart  = (int*)(p + gstart_off);
    int*    deg     = (int*)(p + deg_off);
    float*  agg0    = (float*)(p + agg0_off);
    int*    incl    = (int*)(p + incl_off);
    int*    cur     = (int*)(p + cur_off);
    int*    bsum    = (int*)(p + bsum_off);
    int*    carry   = (int*)(p + carry_off);
    int2*   meta    = (int2*)(p + meta_off);
    f16*    Wf      = (f16*)(p + wf_off);
    int2*   pairs   = (int2*)(p + pairs_off);
    f16*    P0      = (f16*)(p + p0_off);
    unsigned char* P8 = (unsigned char*)(p + p8_off);
    f16*    P1      = (f16*)(p + p1_off);

    hipMemsetAsync(d_ws, 0, zero_bytes, stream);

    int gblk = (N + 63) / 64;
    int abl = (N * 64 + 255) / 256;

    k_cnt<<<EBLK, 256, 0, stream>>>(dstI, deg, E);
    k_prep<<<14, 1024, 0, stream>>>(W2_0, W1_s, W2_s, Wf);
    k_gseg<<<(N + 255) / 256, 256, 0, stream>>>(batch, gcount, gstart, N);
    k_scan1<<<NSB, 1024, 0, stream>>>(deg, incl, bsum, N);
    k_scan2<<<1, 128, 0, stream>>>(bsum, carry, NSB);
    k_scan3<<<NSB, 1024, 0, stream>>>(deg, incl, carry, meta, cur, N);
    k_place<<<EBLK, 256, 0, stream>>>(srcI, dstI, eattr, x, cur, pairs,
                                      agg0, E);

    // Wf plane bases: g=0 -> W2_0; g=1+2l -> W1_s[l]; g=2+2l -> W2_s[l]
    #define WFG(g) (Wf + (size_t)(g) * 16384)

    // layer 0: (x+agg0) rank1-expand + GEMM(W2_0) -> P0 (f16 + fp8 shadow)
    k_mlp0<<<gblk, 256, 0, stream>>>(x, agg0, W1_0, b1_0, WFG(0), b2_0,
                                     P0, P8, N);

    // layers 1..3: agg (P8 gather, P0 self -> P1) + MLP (P1 -> P0 [+P8])
    for (int l = 0; l < 3; ++l) {
        const float* b1 = b1_s + (size_t)l * HID;
        const float* b2 = b2_s + (size_t)l * HID;
        k_agg<<<abl, 256, 0, stream>>>(P8, P0, pairs, meta, P1, N);
        k_mlp<<<gblk, 256, 0, stream>>>(P1, WFG(1 + 2 * l), b1,
                                        WFG(2 + 2 * l), b2, P0, P8,
                                        (l < 2) ? 1 : 0, N);
    }

    k_head<<<G, 256, 0, stream>>>(P0, gstart, gcount, Wc, bc,
                                  (float*)d_out, G);
}

// Round 3
// 330.925 us; speedup vs baseline: 1.5468x; 1.5468x over previous
//
#include <hip/hip_runtime.h>
#include <hip/hip_bf16.h>

// ---------------------------------------------------------------------------
// GINE GNN. Features: f16 plane (self/MLP) + fp8-e4m3 shadow plane gathered
// by k_agg (halves per-XCD L2-fill). CSR: single-pass bucket binning (which
// also precomputes layer-0 edge messages, hiding the x[src] gather under
// k_bin2's TLP) + per-bucket sort with REGISTER edge staging and DIRECT
// pairs writes (block-exclusive contiguous ~24KB region -> single-XCD
// L2-resident, no cross-XCD write amplification; LDS down to 1.5KB).
// Lesson from r2: global fine-grained scatter across XCDs costs ~12x HBM
// write amplification -- keep all scatter inside block-local regions.
// Weights prefragmented f16 MFMA.
// ---------------------------------------------------------------------------

#define HID 128
#define NCLS 3
#define EPB 8192          // edges per binning block
#define BSHIFT 7          // bucket = dst >> 7 (128 nodes/bucket)
#define BNODES 128
#define ECAP 3072         // edges capacity per bucket region (~+22 sigma)

typedef _Float16 f16;
typedef f16 f16x2 __attribute__((ext_vector_type(2)));
typedef f16 f16x8 __attribute__((ext_vector_type(8)));
typedef float f32x2 __attribute__((ext_vector_type(2)));
typedef float f32x4 __attribute__((ext_vector_type(4)));
typedef unsigned short ushort;

__device__ __forceinline__ float bcf(int v) {
    return __builtin_bit_cast(float, v);
}
__device__ __forceinline__ float f16bits2f(ushort u) {
    return (float)__builtin_bit_cast(f16, u);
}

// ---- CSR build: ONE pass count+reserve+place; precompute layer-0 msg ------

__global__ __launch_bounds__(256) void k_bin2(const int* __restrict__ src,
                                              const int* __restrict__ dst,
                                              const float* __restrict__ eattr,
                                              const float* __restrict__ x,
                                              int* __restrict__ cursor,
                                              int2* __restrict__ ebuf,
                                              int E, int NB) {
    __shared__ int lh[1024];
    __shared__ int lbase[1024];
    int t = threadIdx.x;
    for (int b = t; b < NB; b += 256) lh[b] = 0;
    __syncthreads();
    int base = blockIdx.x * EPB;
    int myd[32];
    #pragma unroll
    for (int j = 0; j < 32; ++j) {
        int e = base + j * 256 + t;
        myd[j] = (e < E) ? dst[e] : -1;
        if (myd[j] >= 0) atomicAdd(&lh[myd[j] >> BSHIFT], 1);
    }
    __syncthreads();
    for (int b = t; b < NB; b += 256) {
        int c = lh[b];
        lbase[b] = (c > 0) ? (b * ECAP + atomicAdd(&cursor[b], c)) : 0;
        lh[b] = 0;
    }
    __syncthreads();
    #pragma unroll
    for (int j = 0; j < 32; ++j) {
        if (myd[j] >= 0) {
            int e = base + j * 256 + t;
            int b = myd[j] >> BSHIFT;
            int s = src[e];
            float at = eattr[e];
            float msg = fmaxf(x[s] + at, 0.f);   // layer-0 message, hidden
            unsigned a16 = __builtin_bit_cast(ushort, (f16)at);
            unsigned m16 = __builtin_bit_cast(ushort, (f16)msg);
            int r = atomicAdd(&lh[b], 1);
            int pos = lbase[b] + r;
            if (pos < (b + 1) * ECAP)          // overflow guard (never hits)
                ebuf[pos] = make_int2(s | ((myd[j] & (BNODES - 1)) << 24),
                                      (int)((a16 << 16) | m16));
        }
    }
}

// ---- prep: blocks 0..13 = W prefragmentation (f16 per-lane MFMA layout);
// block 14 = exclusive scan of bucket totals.

__global__ __launch_bounds__(1024) void k_prep(const float* __restrict__ W2_0,
                                               const float* __restrict__ W1_s,
                                               const float* __restrict__ W2_s,
                                               f16* __restrict__ Wf,
                                               const int* __restrict__ cursor,
                                               int* __restrict__ bbase, int NB) {
    int t = threadIdx.x;
    if (blockIdx.x < 14) {
        int id = blockIdx.x * 1024 + t;         // [0, 14336)
        int lane = id & 63;
        int w    = (id >> 6) & 3;
        int nf   = (id >> 8) & 1;
        int kk   = (id >> 9) & 3;
        int g    = id >> 11;
        const float* W = (g == 0) ? W2_0
                       : ((g & 1) ? W1_s + (size_t)((g - 1) >> 1) * HID * HID
                                  : W2_s + (size_t)((g - 2) >> 1) * HID * HID);
        int col = w * 32 + nf * 16 + (lane & 15);
        int k0  = kk * 32 + (lane >> 4) * 8;
        f16x8 hi;
        #pragma unroll
        for (int j = 0; j < 8; ++j)
            hi[j] = (f16)W[(k0 + j) * HID + col];
        size_t o = ((((size_t)g * 4 + kk) * 2 + nf) * 4 + w) * 512 +
                   (size_t)lane * 8;
        *(f16x8*)&Wf[o] = hi;
    } else {
        __shared__ int sd[1024];
        int v = (t < NB) ? min(cursor[t], ECAP) : 0;
        sd[t] = v;
        __syncthreads();
        #pragma unroll
        for (int o = 1; o < 1024; o <<= 1) {
            int add = (t >= o) ? sd[t - o] : 0;
            __syncthreads();
            sd[t] += add;
            __syncthreads();
        }
        if (t < NB) bbase[t] = sd[t] - v;
        if (t == 0) bbase[NB] = sd[NB - 1];
    }
}

// per-bucket (128 nodes): single global read into REGISTERS (<=6 edges per
// thread, statically unrolled so no scratch); count via LDS atomics; scan of
// 128 counters by wave 0 alone via shfl; place DIRECTLY to global pairs
// (block-exclusive contiguous region -> L2-absorbed, written back once).
// LDS = 1.5KB. pairs.x = src*128 byte offset; pairs.y = f32 attr bits.
__global__ __launch_bounds__(512, 8) void k_fill2(const int2* __restrict__ ebuf,
                                               const int* __restrict__ btot,
                                               const int* __restrict__ bbase,
                                               const float* __restrict__ x,
                                               const int* __restrict__ batch,
                                               int2* __restrict__ meta,
                                               int2* __restrict__ pairs,
                                               float* __restrict__ hin0,
                                               int* __restrict__ gcount,
                                               int* __restrict__ gstart,
                                               int N) {
    __shared__ int lcnt[BNODES];
    __shared__ int lofs[BNODES];
    __shared__ float satom[BNODES];
    int b = blockIdx.x, t = threadIdx.x;
    int estart = b * ECAP;
    int cnt = min(btot[b], ECAP);
    int pstart = bbase[b];
    int nb0 = b << BSHIFT;
    if (t < BNODES) {
        lcnt[t] = 0;
        satom[t] = 0.f;
        int node = nb0 + t;                    // graph-segment prep
        if (node < N) {
            int gb = batch[node];
            atomicAdd(&gcount[gb], 1);
            if (node == 0 || batch[node - 1] != gb) gstart[gb] = node;
        }
    }
    __syncthreads();
    // load edges into registers: 6 independent loads in flight, then count
    int2 myv[6];
    #pragma unroll
    for (int j = 0; j < 6; ++j) {
        int i = j * 512 + t;
        if (i < cnt) myv[j] = ebuf[estart + i];
    }
    #pragma unroll
    for (int j = 0; j < 6; ++j) {
        int i = j * 512 + t;
        if (i < cnt) atomicAdd(&lcnt[((unsigned)myv[j].x) >> 24], 1);
    }
    __syncthreads();
    // wave 0 scans all 128 counters via shfl (2 elems/lane, no barriers)
    if (t < 64) {
        int a  = lcnt[t], b2 = lcnt[t + 64];
        int sa = a;
        #pragma unroll
        for (int o = 1; o < 64; o <<= 1) {
            int v = __shfl_up(sa, o);
            if (t >= o) sa += v;
        }
        int sb = b2;
        #pragma unroll
        for (int o = 1; o < 64; o <<= 1) {
            int v = __shfl_up(sb, o);
            if (t >= o) sb += v;
        }
        sb += __shfl(sa, 63);
        int ea = sa - a, eb = sb - b2;        // exclusive offsets
        lofs[t] = ea;  lofs[t + 64] = eb;
        lcnt[t] = 0;   lcnt[t + 64] = 0;
        int n0 = nb0 + t, n1 = nb0 + 64 + t;
        if (n0 < N) meta[n0] = make_int2(pstart + ea, a);
        if (n1 < N) meta[n1] = make_int2(pstart + eb, b2);
    }
    __syncthreads();
    // place: direct global write (region is block-exclusive, L2-resident);
    // satom adds the precomputed f16 message
    #pragma unroll
    for (int j = 0; j < 6; ++j) {
        int i = j * 512 + t;
        if (i < cnt) {
            int2 v = myv[j];
            int ld = ((unsigned)v.x) >> 24;
            int srcid = v.x & 0x00FFFFFF;
            ushort a16 = (ushort)(((unsigned)v.y) >> 16);
            ushort m16 = (ushort)(v.y & 0xFFFF);
            int r = atomicAdd(&lcnt[ld], 1);
            int pos = lofs[ld] + r;
            pairs[pstart + pos] = make_int2(srcid << 7,
                                 __builtin_bit_cast(int, f16bits2f(a16)));
            atomicAdd(&satom[ld], f16bits2f(m16));
        }
    }
    __syncthreads();
    if (t < BNODES) {
        int node = nb0 + t;
        if (node < N) hin0[node] = x[node] + satom[t];
    }
}

// ---- 128-wide aggregation: wave/node, fp8 gather, f32 packed math ---------

__device__ __forceinline__ void agg_add8(f32x2 acc2[4], uint2 g, float e) {
    f32x2 e2 = {e, e}, z2 = {0.f, 0.f};
    unsigned gw[2] = {g.x, g.y};
    #pragma unroll
    for (int ww = 0; ww < 2; ++ww) {
        f32x2 lo = __builtin_amdgcn_cvt_pk_f32_fp8((int)gw[ww], false);
        f32x2 hi = __builtin_amdgcn_cvt_pk_f32_fp8((int)gw[ww], true);
        lo = __builtin_elementwise_max(lo + e2, z2);
        hi = __builtin_elementwise_max(hi + e2, z2);
        acc2[2 * ww]     += lo;
        acc2[2 * ww + 1] += hi;
    }
}

__device__ __forceinline__ uint2 agg_ld8(const char* __restrict__ hb,
                                         int voff) {
    return *(const uint2*)(hb + (unsigned)voff);
}

__global__ __launch_bounds__(256) void k_agg(const unsigned char* __restrict__ h8,
                                             const f16* __restrict__ hf,
                                             const int2* __restrict__ pairs,
                                             const int2* __restrict__ meta,
                                             f16* __restrict__ oh, int n) {
    int gw = (blockIdx.x * 256 + threadIdx.x) >> 6;
    if (gw >= n) return;               // wave-uniform exit
    int lane = threadIdx.x & 63;
    int q = lane >> 4, c = lane & 15;
    int c8 = c * 8;
    const char* hb = (const char*)h8;
    int2 m = meta[gw];
    int off = m.x, d = m.y;
    f32x2 acc2[4] = {{0.f,0.f},{0.f,0.f},{0.f,0.f},{0.f,0.f}};

    int2 mypr = make_int2(0, 0);
    if (lane < d) mypr = pairs[off + lane];
    int lim = d < 64 ? d : 64;

    int pb = 0;
    for (; pb + 16 <= lim; pb += 16) {          // wave-uniform bound
        int p0 = pb + q;
        int s0 = __shfl(mypr.x, p0);
        int s1 = __shfl(mypr.x, p0 + 4);
        int s2 = __shfl(mypr.x, p0 + 8);
        int s3 = __shfl(mypr.x, p0 + 12);
        float e0 = bcf(__shfl(mypr.y, p0));
        float e1 = bcf(__shfl(mypr.y, p0 + 4));
        float e2 = bcf(__shfl(mypr.y, p0 + 8));
        float e3 = bcf(__shfl(mypr.y, p0 + 12));
        uint2 g0 = agg_ld8(hb, s0 + c8);
        uint2 g1 = agg_ld8(hb, s1 + c8);
        uint2 g2 = agg_ld8(hb, s2 + c8);
        uint2 g3 = agg_ld8(hb, s3 + c8);
        agg_add8(acc2, g0, e0);
        agg_add8(acc2, g1, e1);
        agg_add8(acc2, g2, e2);
        agg_add8(acc2, g3, e3);
    }
    if (pb < lim) {
        // single predicated step: pb <= 48 so all shuffle sources <= 63
        int pe = pb + q;
        int s0 = __shfl(mypr.x, pe);
        int s1 = __shfl(mypr.x, pe + 4);
        int s2 = __shfl(mypr.x, pe + 8);
        int s3 = __shfl(mypr.x, pe + 12);
        float e0 = bcf(__shfl(mypr.y, pe));
        float e1 = bcf(__shfl(mypr.y, pe + 4));
        float e2 = bcf(__shfl(mypr.y, pe + 8));
        float e3 = bcf(__shfl(mypr.y, pe + 12));
        uint2 g0 = agg_ld8(hb, s0 + c8);
        uint2 g1 = agg_ld8(hb, s1 + c8);
        uint2 g2 = agg_ld8(hb, s2 + c8);
        uint2 g3 = agg_ld8(hb, s3 + c8);
        if (pe < lim)      agg_add8(acc2, g0, e0);
        if (pe + 4 < lim)  agg_add8(acc2, g1, e1);
        if (pe + 8 < lim)  agg_add8(acc2, g2, e2);
        if (pe + 12 < lim) agg_add8(acc2, g3, e3);
    }
    for (int p = 64 + q; p < d; p += 4) {        // deg>64 tail, no shuffles
        int2 pr = pairs[off + p];
        agg_add8(acc2, agg_ld8(hb, pr.x + c8), bcf(pr.y));
    }

    #pragma unroll
    for (int ww = 0; ww < 4; ++ww) {
        acc2[ww].x += __shfl_xor(acc2[ww].x, 16);
        acc2[ww].x += __shfl_xor(acc2[ww].x, 32);
        acc2[ww].y += __shfl_xor(acc2[ww].y, 16);
        acc2[ww].y += __shfl_xor(acc2[ww].y, 32);
    }
    if (q == 0) {
        uint4 sg = *(const uint4*)&hf[(size_t)gw * HID + c * 8];
        unsigned sw[4] = {sg.x, sg.y, sg.z, sg.w};
        unsigned ow[4];
        #pragma unroll
        for (int ww = 0; ww < 4; ++ww) {
            f16x2 s = __builtin_bit_cast(f16x2, sw[ww]);
            f16x2 o;
            o[0] = (f16)((float)s[0] + acc2[ww].x);
            o[1] = (f16)((float)s[1] + acc2[ww].y);
            ow[ww] = __builtin_bit_cast(unsigned, o);
        }
        uint4 o4;
        o4.x = ow[0]; o4.y = ow[1]; o4.z = ow[2]; o4.w = ow[3];
        *(uint4*)&oh[(size_t)gw * HID + c * 8] = o4;
    }
}

// ---- MLP helpers (single-product f16 weights) -----------------------------

__device__ __forceinline__ void load_wfrags1(const f16* __restrict__ Wfg,
                                             int w, int lane,
                                             f16x8 whf[4][2]) {
    #pragma unroll
    for (int kk = 0; kk < 4; ++kk)
        #pragma unroll
        for (int nf = 0; nf < 2; ++nf) {
            size_t o = (((size_t)kk * 2 + nf) * 4 + w) * 512 +
                       (size_t)lane * 8;
            whf[kk][nf] = *(const f16x8*)&Wfg[o];
        }
}

__device__ __forceinline__ void do_gemm1(const f16* Ah,
                                         const f16x8 whf[4][2],
                                         int lane, f32x4 acc[4][2]) {
    int arow = lane & 15, akgrp = lane >> 4;
    #pragma unroll
    for (int kk = 0; kk < 4; ++kk) {
        int chunk = kk * 4 + akgrp;
        f16x8 ah[4];
        #pragma unroll
        for (int mf = 0; mf < 4; ++mf) {
            int r = mf * 16 + arow;
            int swz = chunk ^ (r & 15);
            ah[mf] = *(const f16x8*)&Ah[r * HID + swz * 8];
        }
        #pragma unroll
        for (int mf = 0; mf < 4; ++mf)
            #pragma unroll
            for (int nf = 0; nf < 2; ++nf)
                acc[mf][nf] = __builtin_amdgcn_mfma_f32_16x16x32_f16(
                    ah[mf], whf[kk][nf], acc[mf][nf], 0, 0, 0);
    }
}

// ---- MLP: O = relu(relu(A@W1+b1)@W2+b2), A f16 plane; fp8 shadow write ----

__global__ __launch_bounds__(256, 3) void k_mlp(
    const f16* __restrict__ A_g,
    const f16* __restrict__ Wf1, const float* __restrict__ b1,
    const f16* __restrict__ Wf2, const float* __restrict__ b2,
    f16* __restrict__ O, unsigned char* __restrict__ O8, int w8, int n) {

    __shared__ __align__(16) f16 bufA[64 * HID];   // A, then T
    int t = threadIdx.x, w = t >> 6, lane = t & 63;
    int wcol = w * 32, fcol = lane & 15, kgrp = lane >> 4;
    int row0 = blockIdx.x * 64;

    #pragma unroll
    for (int rep = 0; rep < 4; ++rep) {
        int task = rep * 256 + t;
        int r = task >> 4, ch = task & 15;
        int gr = min(row0 + r, n - 1);
        int swz = ch ^ (r & 15);
        *(f16x8*)&bufA[r * HID + swz * 8] =
            *(const f16x8*)&A_g[(size_t)gr * HID + ch * 8];
    }

    f32x4 acc[4][2];
    {
        f16x8 whf[4][2];
        load_wfrags1(Wf1, w, lane, whf);
        float bv0 = b1[wcol + fcol], bv1 = b1[wcol + 16 + fcol];
        __syncthreads();
        #pragma unroll
        for (int mf = 0; mf < 4; ++mf)
            #pragma unroll
            for (int nf = 0; nf < 2; ++nf)
                acc[mf][nf] = (f32x4)(0.f);
        do_gemm1(bufA, whf, lane, acc);
        __syncthreads();   // all A reads done before T overwrites
        #pragma unroll
        for (int mf = 0; mf < 4; ++mf)
            #pragma unroll
            for (int nf = 0; nf < 2; ++nf) {
                int cc = wcol + nf * 16 + fcol;
                float bb = nf ? bv1 : bv0;
                #pragma unroll
                for (int j = 0; j < 4; ++j) {
                    int r = mf * 16 + kgrp * 4 + j;
                    float v = fmaxf(acc[mf][nf][j] + bb, 0.f);
                    int addr = r * HID + (((cc >> 3) ^ (r & 15)) << 3) + (cc & 7);
                    bufA[addr] = (f16)v;
                }
            }
    }
    {
        f16x8 whf[4][2];
        load_wfrags1(Wf2, w, lane, whf);
        float bv0 = b2[wcol + fcol], bv1 = b2[wcol + 16 + fcol];
        __syncthreads();
        #pragma unroll
        for (int mf = 0; mf < 4; ++mf)
            #pragma unroll
            for (int nf = 0; nf < 2; ++nf)
                acc[mf][nf] = (f32x4)(0.f);
        do_gemm1(bufA, whf, lane, acc);

        #pragma unroll
        for (int mf = 0; mf < 4; ++mf)
            #pragma unroll
            for (int nf = 0; nf < 2; ++nf) {
                int cc = wcol + nf * 16 + fcol;
                float bb = nf ? bv1 : bv0;
                #pragma unroll
                for (int j = 0; j < 4; ++j) {
                    int r = row0 + mf * 16 + kgrp * 4 + j;
                    if (r < n) {
                        float v = fmaxf(acc[mf][nf][j] + bb, 0.f);
                        O[(size_t)r * HID + cc] = (f16)v;
                        if (w8) {
                            int pk = __builtin_amdgcn_cvt_pk_fp8_f32(
                                v, v, 0, false);
                            O8[(size_t)r * HID + cc] =
                                (unsigned char)(pk & 0xFF);
                        }
                    }
                }
            }
    }
}

// ---- layer-0 MLP (rank-1 expansion fused) ---------------------------------

__global__ __launch_bounds__(256, 3) void k_mlp0(
    const float* __restrict__ r1x, const float* __restrict__ r1w,
    const float* __restrict__ r1b,
    const f16* __restrict__ Wf2, const float* __restrict__ b2,
    f16* __restrict__ O, unsigned char* __restrict__ O8, int n) {

    __shared__ __align__(16) f16 bufA[64 * HID];
    int t = threadIdx.x, w = t >> 6, lane = t & 63;
    int wcol = w * 32, fcol = lane & 15, kgrp = lane >> 4;
    int row0 = blockIdx.x * 64;

    #pragma unroll
    for (int rep = 0; rep < 4; ++rep) {
        int task = rep * 256 + t;
        int r = task >> 4, ch = task & 15;
        int gr = min(row0 + r, n - 1);
        int swz = ch ^ (r & 15);
        float xv = r1x[gr];
        f16x8 hi;
        #pragma unroll
        for (int j = 0; j < 8; ++j)
            hi[j] = (f16)fmaxf(xv * r1w[ch * 8 + j] + r1b[ch * 8 + j], 0.f);
        *(f16x8*)&bufA[r * HID + swz * 8] = hi;
    }

    f16x8 whf[4][2];
    load_wfrags1(Wf2, w, lane, whf);
    float bv0 = b2[wcol + fcol], bv1 = b2[wcol + 16 + fcol];
    __syncthreads();
    f32x4 acc[4][2];
    #pragma unroll
    for (int mf = 0; mf < 4; ++mf)
        #pragma unroll
        for (int nf = 0; nf < 2; ++nf)
            acc[mf][nf] = (f32x4)(0.f);
    do_gemm1(bufA, whf, lane, acc);

    #pragma unroll
    for (int mf = 0; mf < 4; ++mf)
        #pragma unroll
        for (int nf = 0; nf < 2; ++nf) {
            int cc = wcol + nf * 16 + fcol;
            float bb = nf ? bv1 : bv0;
            #pragma unroll
            for (int j = 0; j < 4; ++j) {
                int r = row0 + mf * 16 + kgrp * 4 + j;
                if (r < n) {
                    float v = fmaxf(acc[mf][nf][j] + bb, 0.f);
                    O[(size_t)r * HID + cc] = (f16)v;
                    int pk = __builtin_amdgcn_cvt_pk_fp8_f32(v, v, 0, false);
                    O8[(size_t)r * HID + cc] = (unsigned char)(pk & 0xFF);
                }
            }
        }
}

// ---- mean pool + head: 256 threads, 4 rows in flight, f16x2 loads ---------

__global__ __launch_bounds__(256) void k_head(const f16* __restrict__ h,
                                              const int* __restrict__ gstart,
                                              const int* __restrict__ gcount,
                                              const float* __restrict__ Wc,
                                              const float* __restrict__ bc,
                                              float* __restrict__ out, int G) {
    __shared__ float2 red[4][64];
    __shared__ float pl[HID];
    int g = blockIdx.x, t = threadIdx.x;
    int rr = t >> 6, cc = t & 63;
    int st = gstart[g], c = gcount[g];
    float2 acc = make_float2(0.f, 0.f);
    for (int i = rr; i < c; i += 4) {
        unsigned u = *(const unsigned*)&h[(size_t)(st + i) * HID + cc * 2];
        f16x2 v = __builtin_bit_cast(f16x2, u);
        acc.x += (float)v[0];
        acc.y += (float)v[1];
    }
    red[rr][cc] = acc;
    __syncthreads();
    if (rr == 0) {
        #pragma unroll
        for (int k = 1; k < 4; ++k) {
            acc.x += red[k][cc].x;
            acc.y += red[k][cc].y;
        }
        float inv = 1.f / fmaxf((float)c, 1.f);
        pl[cc * 2]     = acc.x * inv;
        pl[cc * 2 + 1] = acc.y * inv;
    }
    __syncthreads();
    if (t < NCLS) {
        float o = bc[t];
        for (int k = 0; k < HID; ++k) o += pl[k] * Wc[k * NCLS + t];
        out[g * NCLS + t] = o;
    }
}

// ---------------------------------------------------------------------------

static inline size_t alignup(size_t x, size_t a) { return (x + a - 1) & ~(a - 1); }

extern "C" void kernel_launch(void* const* d_in, const int* in_sizes, int n_in,
                              void* d_out, int out_size, void* d_ws, size_t ws_size,
                              hipStream_t stream) {
    const float* x      = (const float*)d_in[0];
    const int*   ei     = (const int*)d_in[1];
    const float* eattr  = (const float*)d_in[2];
    const int*   batch  = (const int*)d_in[3];
    const float* W1_0   = (const float*)d_in[4];
    const float* b1_0   = (const float*)d_in[5];
    const float* W2_0   = (const float*)d_in[6];
    const float* b2_0   = (const float*)d_in[7];
    const float* W1_s   = (const float*)d_in[8];
    const float* b1_s   = (const float*)d_in[9];
    const float* W2_s   = (const float*)d_in[10];
    const float* b2_s   = (const float*)d_in[11];
    const float* Wc     = (const float*)d_in[12];
    const float* bc     = (const float*)d_in[13];

    const int N = in_sizes[0];          // 100000
    const int E = in_sizes[2];          // 1600000
    const int G = out_size / NCLS;      // 1000
    const int* srcI = ei;
    const int* dstI = ei + E;

    const int NB = (N + BNODES - 1) >> BSHIFT;          // 782 buckets
    const int NBLK = (E + EPB - 1) / EPB;               // 196 binning blocks

    char* p = (char*)d_ws;
    size_t off = 0;
    size_t gcount_off = off;         off = alignup(off + (size_t)G * 4, 256);
    size_t gstart_off = off;         off = alignup(off + (size_t)G * 4, 256);
    size_t cursor_off = off;         off = alignup(off + 1024 * 4, 256);
    size_t zero_bytes = off;
    size_t meta_off = off;           off = alignup(off + (size_t)N * 8, 256);
    size_t bbase_off = off;          off = alignup(off + 1025 * 4, 256);
    size_t hin0_off = off;           off = alignup(off + (size_t)N * 4, 256);
    size_t wf_off = off;             off = alignup(off + 7 * 16384 * 2, 256);
    size_t pairs_off = off;          off = alignup(off + (size_t)E * 8, 256);
    size_t p0_off = off;             off = alignup(off + (size_t)N * HID * 2, 256);
    size_t p8_off = off;             off = alignup(off + (size_t)N * HID, 256);
    size_t p1_off = off;             off = alignup(off + (size_t)N * HID * 2, 256);

    int*    gcount  = (int*)(p + gcount_off);
    int*    gstart  = (int*)(p + gstart_off);
    int*    cursor  = (int*)(p + cursor_off);
    int2*   meta    = (int2*)(p + meta_off);
    int*    bbase   = (int*)(p + bbase_off);
    float*  hin0    = (float*)(p + hin0_off);
    f16*    Wf      = (f16*)(p + wf_off);
    int2*   pairs   = (int2*)(p + pairs_off);
    f16*    P0      = (f16*)(p + p0_off);
    unsigned char* P8 = (unsigned char*)(p + p8_off);
    f16*    P1      = (f16*)(p + p1_off);
    // ebuf aliases P1 (dead until layer-1's k_agg writes P1):
    // NB*ECAP*8B = 782*3072*8 = 19.2MB <= N*HID*2B = 25.6MB
    int2*   ebuf    = (int2*)(p + p1_off);

    hipMemsetAsync(d_ws, 0, zero_bytes, stream);

    int gblk = (N + 63) / 64;
    int abl = (N * 64 + 255) / 256;

    k_bin2<<<NBLK, 256, 0, stream>>>(srcI, dstI, eattr, x, cursor, ebuf, E, NB);
    k_prep<<<15, 1024, 0, stream>>>(W2_0, W1_s, W2_s, Wf, cursor, bbase, NB);
    k_fill2<<<NB, 512, 0, stream>>>(ebuf, cursor, bbase, x, batch, meta,
                                    pairs, hin0, gcount, gstart, N);

    // Wf plane bases: g=0 -> W2_0; g=1+2l -> W1_s[l]; g=2+2l -> W2_s[l]
    #define WFG(g) (Wf + (size_t)(g) * 16384)

    // layer 0: rank1-expand + GEMM(W2_0) -> P0 (f16 + fp8 shadow)
    k_mlp0<<<gblk, 256, 0, stream>>>(hin0, W1_0, b1_0, WFG(0), b2_0,
                                     P0, P8, N);

    // layers 1..3: agg (P8 gather, P0 self -> P1) + MLP (P1 -> P0 [+P8])
    for (int l = 0; l < 3; ++l) {
        const float* b1 = b1_s + (size_t)l * HID;
        const float* b2 = b2_s + (size_t)l * HID;
        k_agg<<<abl, 256, 0, stream>>>(P8, P0, pairs, meta, P1, N);
        k_mlp<<<gblk, 256, 0, stream>>>(P1, WFG(1 + 2 * l), b1,
                                        WFG(2 + 2 * l), b2, P0, P8,
                                        (l < 2) ? 1 : 0, N);
    }

    k_head<<<G, 256, 0, stream>>>(P0, gstart, gcount, Wc, bc,
                                  (float*)d_out, G);
}